// Round 12
// baseline (661.367 us; speedup 1.0000x reference)
//
#include <hip/hip_runtime.h>
#include <math.h>

#define F_IN 512
#define HD 64
#define CD 16
#define K_HOPS 10

#define BKT_SHIFT 7
#define BKT_NODES 128
#define NBKT_MAX 1024
#define EPB 8192

#define HOP_BLOCKS 2048

typedef unsigned int uint32;
typedef __attribute__((ext_vector_type(8))) short short8v;
typedef __attribute__((ext_vector_type(4))) float float4v;

static __device__ __forceinline__ float bf2f(unsigned short h) {
    return __uint_as_float(((uint32)h) << 16);
}
static __device__ __forceinline__ unsigned short f2bf(float x) {
    uint32 u = __float_as_uint(x);
    u = (u + 0x7FFFu + ((u >> 16) & 1u)) >> 16;   // RNE
    return (unsigned short)u;
}

// ---------------- CSR build: two-level bucket sort ----------------

__global__ void zero_kernel(int* __restrict__ p, int n) {
    int i = blockIdx.x * blockDim.x + threadIdx.x;
    if (i < n) p[i] = 0;
}

__global__ __launch_bounds__(256) void bucket_hist_kernel(
    const int* __restrict__ cols, int* __restrict__ bcnt, int e, int nb) {
    __shared__ int c[NBKT_MAX];
    int t = threadIdx.x;
    for (int i = t; i < nb; i += 256) c[i] = 0;
    __syncthreads();
    int base = blockIdx.x * EPB;
    int end = min(base + EPB, e);
    for (int i = base + t; i < end; i += 256)
        atomicAdd(&c[cols[i] >> BKT_SHIFT], 1);
    __syncthreads();
    for (int i = t; i < nb; i += 256)
        if (c[i]) atomicAdd(&bcnt[i], c[i]);
}

__global__ __launch_bounds__(256) void bucket_scan_kernel(
    const int* __restrict__ bcnt, int* __restrict__ bstart,
    int* __restrict__ bcur, int nb) {
    __shared__ int s[256];
    int t = threadIdx.x;
    int v[4]; int sum = 0;
#pragma unroll
    for (int i = 0; i < 4; ++i) {
        int idx = t * 4 + i;
        v[i] = (idx < nb) ? bcnt[idx] : 0;
        sum += v[i];
    }
    s[t] = sum; __syncthreads();
    for (int off = 1; off < 256; off <<= 1) {
        int x = (t >= off) ? s[t - off] : 0;
        __syncthreads();
        s[t] += x;
        __syncthreads();
    }
    int excl = s[t] - sum;
#pragma unroll
    for (int i = 0; i < 4; ++i) {
        int idx = t * 4 + i;
        if (idx < nb) { bstart[idx] = excl; bcur[idx] = excl; }
        excl += v[i];
    }
    if (t == 255) bstart[nb] = excl;
}

__global__ __launch_bounds__(256) void scatter_bin_kernel(
    const int* __restrict__ rows, const int* __restrict__ cols,
    int* __restrict__ bcur, uint32* __restrict__ stage, int e, int nb) {
    __shared__ int c[NBKT_MAX];
    int t = threadIdx.x;
    for (int i = t; i < nb; i += 256) c[i] = 0;
    __syncthreads();
    int base = blockIdx.x * EPB;
    int end = min(base + EPB, e);
    for (int i = base + t; i < end; i += 256)
        atomicAdd(&c[cols[i] >> BKT_SHIFT], 1);
    __syncthreads();
    for (int i = t; i < nb; i += 256) {
        int cc = c[i];
        if (cc) c[i] = atomicAdd(&bcur[i], cc);
    }
    __syncthreads();
    for (int i = base + t; i < end; i += 256) {
        int col = cols[i];
        int b = col >> BKT_SHIFT;
        int pos = atomicAdd(&c[b], 1);
        stage[pos] = ((uint32)rows[i] << BKT_SHIFT) | (uint32)(col & (BKT_NODES - 1));
    }
}

__global__ __launch_bounds__(256) void bucket_sort_kernel(
    const uint32* __restrict__ stage, const int* __restrict__ bstart,
    int* __restrict__ rowstart, float* __restrict__ dis,
    int* __restrict__ csr, int n, int e) {
    __shared__ int cnt[BKT_NODES];
    __shared__ int excl[BKT_NODES];
    __shared__ int lcur[BKT_NODES];
    int b = blockIdx.x, t = threadIdx.x;
    int s0 = bstart[b], s1 = bstart[b + 1];
    int nnode = min(BKT_NODES, n - b * BKT_NODES);
    if (t < BKT_NODES) cnt[t] = 0;
    __syncthreads();
    for (int i = s0 + t; i < s1; i += 256)
        atomicAdd(&cnt[stage[i] & (BKT_NODES - 1)], 1);
    __syncthreads();
    if (t < BKT_NODES) excl[t] = cnt[t];
    __syncthreads();
    for (int off = 1; off < BKT_NODES; off <<= 1) {
        int x = 0;
        if (t < BKT_NODES && t >= off) x = excl[t - off];
        __syncthreads();
        if (t < BKT_NODES) excl[t] += x;
        __syncthreads();
    }
    if (t < BKT_NODES) {
        int rs = s0 + excl[t] - cnt[t];
        lcur[t] = rs;
        if (t < nnode) {
            rowstart[b * BKT_NODES + t] = rs;
            dis[b * BKT_NODES + t] = rsqrtf((float)(cnt[t] + 1));
        }
    }
    if (b == 0 && t == 0) rowstart[n] = e;
    __syncthreads();
    for (int i = s0 + t; i < s1; i += 256) {
        uint32 v = stage[i];
        int pos = atomicAdd(&lcur[v & (BKT_NODES - 1)], 1);
        csr[pos] = (int)(v >> BKT_SHIFT);
    }
}

// ---------------- weight transpose + bf16 convert (one-time) -------------

__global__ void convw_kernel(const float* __restrict__ W1,
                             const float* __restrict__ W2,
                             unsigned short* __restrict__ w1t,
                             unsigned short* __restrict__ w2t) {
    int i = blockIdx.x * blockDim.x + threadIdx.x;
    if (i < HD * F_IN) {
        int h = i >> 9, k = i & 511;
        w1t[i] = f2bf(W1[k * HD + h]);
    } else {
        int j = i - HD * F_IN;
        if (j < CD * HD) {
            int c = j >> 6, k = j & 63;
            w2t[j] = f2bf(W2[k * CD + c]);
        }
    }
}

// ---------------- MFMA MLP + riemann + init ------------------------------

#define LSTR 72

__global__ __launch_bounds__(256) void mlp_kernel(
    const float* __restrict__ x, const unsigned short* __restrict__ w1t,
    const float* __restrict__ b1, const unsigned short* __restrict__ w2t,
    const float* __restrict__ b2, const float* __restrict__ dis,
    const float* __restrict__ temp, const float* __restrict__ wfn,
    unsigned short* __restrict__ g0, float* __restrict__ hidden, int n) {
    __shared__ __align__(16) unsigned short xb[64 * LSTR];
    __shared__ __align__(16) unsigned short w1b[64 * LSTR];
    __shared__ __align__(16) unsigned short w2b[16 * LSTR];

    const int t = threadIdx.x;
    const int row0 = blockIdx.x * 64;
    const int wave = t >> 6, lane = t & 63;
    const int l15 = lane & 15, lq = lane >> 4;
    const int lrow = (wave << 4) + l15;

    if (t < 128) {
        int cr = t >> 3, part = t & 7;
        *(short8v*)&w2b[cr * LSTR + part * 8] =
            *(const short8v*)&w2t[cr * HD + part * 8];
    }

    float4v acc[4];
#pragma unroll
    for (int i = 0; i < 4; ++i) acc[i] = (float4v)0.0f;

    const int srow = t >> 2, spart = t & 3;
    for (int c = 0; c < F_IN / 64; ++c) {
        __syncthreads();
        {
            int gr = row0 + srow; if (gr >= n) gr = n - 1;
            const float* xp = x + (long)gr * F_IN + c * 64 + spart * 16;
            float4 v0 = *(const float4*)(xp + 0);
            float4 v1 = *(const float4*)(xp + 4);
            float4 v2 = *(const float4*)(xp + 8);
            float4 v3 = *(const float4*)(xp + 12);
            short8v o0, o1;
            o0[0] = (short)f2bf(v0.x); o0[1] = (short)f2bf(v0.y);
            o0[2] = (short)f2bf(v0.z); o0[3] = (short)f2bf(v0.w);
            o0[4] = (short)f2bf(v1.x); o0[5] = (short)f2bf(v1.y);
            o0[6] = (short)f2bf(v1.z); o0[7] = (short)f2bf(v1.w);
            o1[0] = (short)f2bf(v2.x); o1[1] = (short)f2bf(v2.y);
            o1[2] = (short)f2bf(v2.z); o1[3] = (short)f2bf(v2.w);
            o1[4] = (short)f2bf(v3.x); o1[5] = (short)f2bf(v3.y);
            o1[6] = (short)f2bf(v3.z); o1[7] = (short)f2bf(v3.w);
            *(short8v*)&xb[srow * LSTR + spart * 16] = o0;
            *(short8v*)&xb[srow * LSTR + spart * 16 + 8] = o1;
            const unsigned short* wp = w1t + srow * F_IN + c * 64 + spart * 16;
            *(short8v*)&w1b[srow * LSTR + spart * 16] = *(const short8v*)(wp);
            *(short8v*)&w1b[srow * LSTR + spart * 16 + 8] = *(const short8v*)(wp + 8);
        }
        __syncthreads();
#pragma unroll
        for (int st = 0; st < 2; ++st) {
            int kb = st * 32 + lq * 8;
            short8v av = *(const short8v*)&xb[lrow * LSTR + kb];
#pragma unroll
            for (int hf = 0; hf < 4; ++hf) {
                short8v bv = *(const short8v*)&w1b[(hf * 16 + l15) * LSTR + kb];
                acc[hf] = __builtin_amdgcn_mfma_f32_16x16x32_bf16(av, bv, acc[hf], 0, 0, 0);
            }
        }
    }

    __syncthreads();
    {
        int drow = (wave << 4) + (lq << 2);
#pragma unroll
        for (int hf = 0; hf < 4; ++hf) {
            int h = hf * 16 + l15;
            float bv = b1[h];
#pragma unroll
            for (int i = 0; i < 4; ++i) {
                float v = acc[hf][i] + bv;
                v = v > 0.0f ? v : 0.0f;
                xb[(drow + i) * LSTR + h] = f2bf(v);
            }
        }
    }
    __syncthreads();

    float4v acc2 = (float4v)0.0f;
#pragma unroll
    for (int st = 0; st < 2; ++st) {
        int kb = st * 32 + lq * 8;
        short8v av = *(const short8v*)&xb[lrow * LSTR + kb];
        short8v bv = *(const short8v*)&w2b[l15 * LSTR + kb];
        acc2 = __builtin_amdgcn_mfma_f32_16x16x32_bf16(av, bv, acc2, 0, 0, 0);
    }

    {
        const int cc = l15;
        const int drow = (wave << 4) + (lq << 2);
        float b2c = b2[cc];
        float wabs = fabsf(wfn[cc]);
        float o[4], p[4];
#pragma unroll
        for (int i = 0; i < 4; ++i) {
            o[i] = acc2[i] + b2c;
            p[i] = o[i] * o[i] * wabs;
        }
#pragma unroll
        for (int off = 1; off < 16; off <<= 1) {
#pragma unroll
            for (int i = 0; i < 4; ++i) p[i] += __shfl_xor(p[i], off);
        }
        float t0 = temp[0];
#pragma unroll
        for (int i = 0; i < 4; ++i) {
            int grow = row0 + drow + i;
            if (grow < n) {
                float inv = 1.0f / (sqrtf(p[i] + 0.01f) + 0.01f);
                float hn = o[i] * inv;
                float d = dis[grow];
                hidden[(long)grow * CD + cc] = t0 * hn;
                g0[(long)grow * CD + cc] = f2bf(d * hn);
            }
        }
    }
}

// ---------------- dual-node hop: 2 interleaved gather chains per wave ----
// wave processes nodes (na, na+NW) concurrently, stride 2*NW. Both nodes'
// round-1 gathers (4x32B) in flight together; tails interleaved; depth-1
// next-pair metadata/csr prefetch. 16 slots x 4 feat-lanes, bf16 (r7).

__global__ __launch_bounds__(256) void hop_kernel(
    const unsigned short* __restrict__ g, unsigned short* __restrict__ gn,
    float* __restrict__ hidden, const float* __restrict__ dis,
    const int* __restrict__ rowstart, const int* __restrict__ csr,
    const float* __restrict__ temp, const float* __restrict__ wfn,
    int kidx, int writeg, int n, int etot) {
    const int wv = (blockIdx.x << 2) + (threadIdx.x >> 6);
    const int NW = gridDim.x << 2;
    if (wv >= n) return;
    const int lane = threadIdx.x & 63;
    const int slot = lane >> 2, fl = lane & 3;
    const float tk = temp[kidx];
    const float4 wq = *(const float4*)(wfn + (fl << 2));
    const float wx = fabsf(wq.x), wy = fabsf(wq.y),
                wz = fabsf(wq.z), ww = fabsf(wq.w);
    const int stride = NW << 1;

    // prologue: first pair
    int na = wv, nb = wv + NW;
    bool bv = nb < n;
    int rs0a = rowstart[na], rs1a = rowstart[na + 1];
    float da = dis[na];
    ushort4 sva = *(const ushort4*)(g + ((long)na << 4) + (fl << 2));
    int rs0b = 0, rs1b = 0; float db = 0.f; ushort4 svb;
    if (bv) {
        rs0b = rowstart[nb]; rs1b = rowstart[nb + 1];
        db = dis[nb];
        svb = *(const ushort4*)(g + ((long)nb << 4) + (fl << 2));
    }
    int c0a = csr[min(rs0a + slot, etot - 1)];
    int c1a = csr[min(rs0a + slot + 16, etot - 1)];
    int c0b = 0, c1b = 0;
    if (bv) {
        c0b = csr[min(rs0b + slot, etot - 1)];
        c1b = csr[min(rs0b + slot + 16, etot - 1)];
    }

    for (;;) {
        const int nna = na + stride, nnb = nb + stride;
        const bool has_next = nna < n;
        const bool bvn = nnb < n;

        // (1) prefetch next pair metadata
        int rs0an, rs1an, rs0bn, rs1bn;
        float dan, dbn; ushort4 svan, svbn;
        if (has_next) {
            rs0an = rowstart[nna]; rs1an = rowstart[nna + 1];
            dan = dis[nna];
            svan = *(const ushort4*)(g + ((long)nna << 4) + (fl << 2));
            if (bvn) {
                rs0bn = rowstart[nnb]; rs1bn = rowstart[nnb + 1];
                dbn = dis[nnb];
                svbn = *(const ushort4*)(g + ((long)nnb << 4) + (fl << 2));
            }
        }

        // (2) round-1 gathers for BOTH nodes (4 scatters in flight)
        float a0 = 0.f, a1 = 0.f, a2 = 0.f, a3 = 0.f;
        float b0 = 0.f, b1 = 0.f, b2 = 0.f, b3 = 0.f;
        if (rs0a + slot < rs1a) {
            ushort4 v = *(const ushort4*)(g + ((long)c0a << 4) + (fl << 2));
            a0 += bf2f(v.x); a1 += bf2f(v.y); a2 += bf2f(v.z); a3 += bf2f(v.w);
        }
        if (rs0a + slot + 16 < rs1a) {
            ushort4 v = *(const ushort4*)(g + ((long)c1a << 4) + (fl << 2));
            a0 += bf2f(v.x); a1 += bf2f(v.y); a2 += bf2f(v.z); a3 += bf2f(v.w);
        }
        if (bv && rs0b + slot < rs1b) {
            ushort4 v = *(const ushort4*)(g + ((long)c0b << 4) + (fl << 2));
            b0 += bf2f(v.x); b1 += bf2f(v.y); b2 += bf2f(v.z); b3 += bf2f(v.w);
        }
        if (bv && rs0b + slot + 16 < rs1b) {
            ushort4 v = *(const ushort4*)(g + ((long)c1b << 4) + (fl << 2));
            b0 += bf2f(v.x); b1 += bf2f(v.y); b2 += bf2f(v.z); b3 += bf2f(v.w);
        }

        // (3) tails, interleaved (2 independent chains)
        {
            int ea = rs0a + slot + 32;
            int eb = bv ? (rs0b + slot + 32) : 0x7FFFFFFF;
            int e1b = bv ? rs1b : 0;
            while (ea < rs1a && eb < e1b) {
                int sa = csr[ea], sb = csr[eb];
                ushort4 va = *(const ushort4*)(g + ((long)sa << 4) + (fl << 2));
                ushort4 vb = *(const ushort4*)(g + ((long)sb << 4) + (fl << 2));
                a0 += bf2f(va.x); a1 += bf2f(va.y); a2 += bf2f(va.z); a3 += bf2f(va.w);
                b0 += bf2f(vb.x); b1 += bf2f(vb.y); b2 += bf2f(vb.z); b3 += bf2f(vb.w);
                ea += 16; eb += 16;
            }
            while (ea < rs1a) {
                int sa = csr[ea];
                ushort4 va = *(const ushort4*)(g + ((long)sa << 4) + (fl << 2));
                a0 += bf2f(va.x); a1 += bf2f(va.y); a2 += bf2f(va.z); a3 += bf2f(va.w);
                ea += 16;
            }
            while (eb < e1b) {
                int sb = csr[eb];
                ushort4 vb = *(const ushort4*)(g + ((long)sb << 4) + (fl << 2));
                b0 += bf2f(vb.x); b1 += bf2f(vb.y); b2 += bf2f(vb.z); b3 += bf2f(vb.w);
                eb += 16;
            }
        }

        // (4) prefetch next pair's round-1 csr
        int c0an, c1an, c0bn, c1bn;
        if (has_next) {
            c0an = csr[min(rs0an + slot, etot - 1)];
            c1an = csr[min(rs0an + slot + 16, etot - 1)];
            if (bvn) {
                c0bn = csr[min(rs0bn + slot, etot - 1)];
                c1bn = csr[min(rs0bn + slot + 16, etot - 1)];
            }
        }

        // (5) butterfly + riemann + write: node a
        {
#pragma unroll
            for (int off = 4; off < 64; off <<= 1) {
                a0 += __shfl_xor(a0, off);
                a1 += __shfl_xor(a1, off);
                a2 += __shfl_xor(a2, off);
                a3 += __shfl_xor(a3, off);
            }
            a0 = (a0 + bf2f(sva.x)) * da;
            a1 = (a1 + bf2f(sva.y)) * da;
            a2 = (a2 + bf2f(sva.z)) * da;
            a3 = (a3 + bf2f(sva.w)) * da;
            float p = a0 * a0 * wx + a1 * a1 * wy + a2 * a2 * wz + a3 * a3 * ww;
            p += __shfl_xor(p, 1);
            p += __shfl_xor(p, 2);
            float inv = 1.0f / (sqrtf(p + 0.01f) + 0.01f);
            if (slot == 0) {
                long base = ((long)na << 4) + (fl << 2);
                float4 hv = *(const float4*)(hidden + base);
                hv.x = fmaf(tk, a0 * inv, hv.x);
                hv.y = fmaf(tk, a1 * inv, hv.y);
                hv.z = fmaf(tk, a2 * inv, hv.z);
                hv.w = fmaf(tk, a3 * inv, hv.w);
                *(float4*)(hidden + base) = hv;
                if (writeg) {
                    ushort4 o;
                    o.x = f2bf(da * a0 * inv); o.y = f2bf(da * a1 * inv);
                    o.z = f2bf(da * a2 * inv); o.w = f2bf(da * a3 * inv);
                    *(ushort4*)(gn + base) = o;
                }
            }
        }

        // (6) butterfly + riemann + write: node b
        if (bv) {
#pragma unroll
            for (int off = 4; off < 64; off <<= 1) {
                b0 += __shfl_xor(b0, off);
                b1 += __shfl_xor(b1, off);
                b2 += __shfl_xor(b2, off);
                b3 += __shfl_xor(b3, off);
            }
            b0 = (b0 + bf2f(svb.x)) * db;
            b1 = (b1 + bf2f(svb.y)) * db;
            b2 = (b2 + bf2f(svb.z)) * db;
            b3 = (b3 + bf2f(svb.w)) * db;
            float p = b0 * b0 * wx + b1 * b1 * wy + b2 * b2 * wz + b3 * b3 * ww;
            p += __shfl_xor(p, 1);
            p += __shfl_xor(p, 2);
            float inv = 1.0f / (sqrtf(p + 0.01f) + 0.01f);
            if (slot == 0) {
                long base = ((long)nb << 4) + (fl << 2);
                float4 hv = *(const float4*)(hidden + base);
                hv.x = fmaf(tk, b0 * inv, hv.x);
                hv.y = fmaf(tk, b1 * inv, hv.y);
                hv.z = fmaf(tk, b2 * inv, hv.z);
                hv.w = fmaf(tk, b3 * inv, hv.w);
                *(float4*)(hidden + base) = hv;
                if (writeg) {
                    ushort4 o;
                    o.x = f2bf(db * b0 * inv); o.y = f2bf(db * b1 * inv);
                    o.z = f2bf(db * b2 * inv); o.w = f2bf(db * b3 * inv);
                    *(ushort4*)(gn + base) = o;
                }
            }
        }

        if (!has_next) break;

        // (7) rotate
        na = nna; nb = nnb; bv = bvn;
        rs0a = rs0an; rs1a = rs1an; da = dan; sva = svan;
        c0a = c0an; c1a = c1an;
        if (bvn) {
            rs0b = rs0bn; rs1b = rs1bn; db = dbn; svb = svbn;
            c0b = c0bn; c1b = c1bn;
        }
    }
}

// ---------------- launch ----------------

static inline long align4up(long w) { return (w + 3) & ~3L; }

extern "C" void kernel_launch(void* const* d_in, const int* in_sizes, int n_in,
                              void* d_out, int out_size, void* d_ws, size_t ws_size,
                              hipStream_t stream) {
    const float* x          = (const float*)d_in[0];
    const int*   edge_index = (const int*)d_in[1];
    const float* W1         = (const float*)d_in[2];
    const float* b1         = (const float*)d_in[3];
    const float* W2         = (const float*)d_in[4];
    const float* b2         = (const float*)d_in[5];
    const float* temp       = (const float*)d_in[6];
    const float* w_for_norm = (const float*)d_in[7];
    float* hidden = (float*)d_out;

    const int n = in_sizes[0] / F_IN;
    const int e = in_sizes[1] / 2;
    const int* rows = edge_index;        // sources
    const int* cols = edge_index + e;    // destinations
    const int nb = (n + BKT_NODES - 1) / BKT_NODES;

    long off = 0;
    int* wsI = (int*)d_ws;
    int* bcnt      = wsI + off; off = align4up(off + NBKT_MAX);
    int* bstart    = wsI + off; off = align4up(off + NBKT_MAX + 1);
    int* bcur      = wsI + off; off = align4up(off + NBKT_MAX);
    int* rowstart  = wsI + off; off = align4up(off + n + 1);
    float* dis     = (float*)(wsI + off); off = align4up(off + n);
    uint32* stage  = (uint32*)(wsI + off); off = align4up(off + e);
    int* csr       = wsI + off; off = align4up(off + e);
    unsigned short* w1t = (unsigned short*)(wsI + off); off = align4up(off + HD * F_IN / 2);
    unsigned short* w2t = (unsigned short*)(wsI + off); off = align4up(off + CD * HD / 2);
    unsigned short* gA  = (unsigned short*)(wsI + off); off = align4up(off + n * 8);
    unsigned short* gB  = (unsigned short*)(wsI + off); off = align4up(off + n * 8);

    const int B = 256;
    const int nbC = (e + EPB - 1) / EPB;

    zero_kernel<<<(nb + B - 1) / B, B, 0, stream>>>(bcnt, nb);
    bucket_hist_kernel<<<nbC, B, 0, stream>>>(cols, bcnt, e, nb);
    bucket_scan_kernel<<<1, B, 0, stream>>>(bcnt, bstart, bcur, nb);
    scatter_bin_kernel<<<nbC, B, 0, stream>>>(rows, cols, bcur, stage, e, nb);
    bucket_sort_kernel<<<nb, B, 0, stream>>>(stage, bstart, rowstart, dis, csr, n, e);
    convw_kernel<<<(HD * F_IN + CD * HD + B - 1) / B, B, 0, stream>>>(W1, W2, w1t, w2t);

    mlp_kernel<<<(n + 63) / 64, B, 0, stream>>>(x, w1t, b1, w2t, b2, dis, temp,
                                                w_for_norm, gA, hidden, n);

    unsigned short* gsrc = gA;
    unsigned short* gdst = gB;
    for (int k = 1; k <= K_HOPS; ++k) {
        hop_kernel<<<HOP_BLOCKS, B, 0, stream>>>(
            gsrc, gdst, hidden, dis, rowstart, csr, temp, w_for_norm,
            k, (k < K_HOPS) ? 1 : 0, n, e);
        unsigned short* tmp = gsrc; gsrc = gdst; gdst = tmp;
    }
}

// Round 13
// 510.575 us; speedup vs baseline: 1.2953x; 1.2953x over previous
//
#include <hip/hip_runtime.h>
#include <math.h>

#define F_IN 512
#define HD 64
#define CD 16
#define K_HOPS 10

#define BKT_SHIFT 7
#define BKT_NODES 128
#define NBKT_MAX 1024
#define EPB 8192

#define HOP_BLOCKS 2048

typedef unsigned int uint32;
typedef __attribute__((ext_vector_type(8))) short short8v;
typedef __attribute__((ext_vector_type(4))) float float4v;

static __device__ __forceinline__ float bf2f(unsigned short h) {
    return __uint_as_float(((uint32)h) << 16);
}
static __device__ __forceinline__ unsigned short f2bf(float x) {
    uint32 u = __float_as_uint(x);
    u = (u + 0x7FFFu + ((u >> 16) & 1u)) >> 16;   // RNE
    return (unsigned short)u;
}

// ---------------- CSR build: two-level bucket sort ----------------

__global__ void zero_kernel(int* __restrict__ p, int n) {
    int i = blockIdx.x * blockDim.x + threadIdx.x;
    if (i < n) p[i] = 0;
}

__global__ __launch_bounds__(256) void bucket_hist_kernel(
    const int* __restrict__ cols, int* __restrict__ bcnt, int e, int nb) {
    __shared__ int c[NBKT_MAX];
    int t = threadIdx.x;
    for (int i = t; i < nb; i += 256) c[i] = 0;
    __syncthreads();
    int base = blockIdx.x * EPB;
    int end = min(base + EPB, e);
    for (int i = base + t; i < end; i += 256)
        atomicAdd(&c[cols[i] >> BKT_SHIFT], 1);
    __syncthreads();
    for (int i = t; i < nb; i += 256)
        if (c[i]) atomicAdd(&bcnt[i], c[i]);
}

__global__ __launch_bounds__(256) void bucket_scan_kernel(
    const int* __restrict__ bcnt, int* __restrict__ bstart,
    int* __restrict__ bcur, int nb) {
    __shared__ int s[256];
    int t = threadIdx.x;
    int v[4]; int sum = 0;
#pragma unroll
    for (int i = 0; i < 4; ++i) {
        int idx = t * 4 + i;
        v[i] = (idx < nb) ? bcnt[idx] : 0;
        sum += v[i];
    }
    s[t] = sum; __syncthreads();
    for (int off = 1; off < 256; off <<= 1) {
        int x = (t >= off) ? s[t - off] : 0;
        __syncthreads();
        s[t] += x;
        __syncthreads();
    }
    int excl = s[t] - sum;
#pragma unroll
    for (int i = 0; i < 4; ++i) {
        int idx = t * 4 + i;
        if (idx < nb) { bstart[idx] = excl; bcur[idx] = excl; }
        excl += v[i];
    }
    if (t == 255) bstart[nb] = excl;
}

__global__ __launch_bounds__(256) void scatter_bin_kernel(
    const int* __restrict__ rows, const int* __restrict__ cols,
    int* __restrict__ bcur, uint32* __restrict__ stage, int e, int nb) {
    __shared__ int c[NBKT_MAX];
    int t = threadIdx.x;
    for (int i = t; i < nb; i += 256) c[i] = 0;
    __syncthreads();
    int base = blockIdx.x * EPB;
    int end = min(base + EPB, e);
    for (int i = base + t; i < end; i += 256)
        atomicAdd(&c[cols[i] >> BKT_SHIFT], 1);
    __syncthreads();
    for (int i = t; i < nb; i += 256) {
        int cc = c[i];
        if (cc) c[i] = atomicAdd(&bcur[i], cc);
    }
    __syncthreads();
    for (int i = base + t; i < end; i += 256) {
        int col = cols[i];
        int b = col >> BKT_SHIFT;
        int pos = atomicAdd(&c[b], 1);
        stage[pos] = ((uint32)rows[i] << BKT_SHIFT) | (uint32)(col & (BKT_NODES - 1));
    }
}

__global__ __launch_bounds__(256) void bucket_sort_kernel(
    const uint32* __restrict__ stage, const int* __restrict__ bstart,
    int* __restrict__ rowstart, float* __restrict__ dis,
    int* __restrict__ csr, int n, int e) {
    __shared__ int cnt[BKT_NODES];
    __shared__ int excl[BKT_NODES];
    __shared__ int lcur[BKT_NODES];
    int b = blockIdx.x, t = threadIdx.x;
    int s0 = bstart[b], s1 = bstart[b + 1];
    int nnode = min(BKT_NODES, n - b * BKT_NODES);
    if (t < BKT_NODES) cnt[t] = 0;
    __syncthreads();
    for (int i = s0 + t; i < s1; i += 256)
        atomicAdd(&cnt[stage[i] & (BKT_NODES - 1)], 1);
    __syncthreads();
    if (t < BKT_NODES) excl[t] = cnt[t];
    __syncthreads();
    for (int off = 1; off < BKT_NODES; off <<= 1) {
        int x = 0;
        if (t < BKT_NODES && t >= off) x = excl[t - off];
        __syncthreads();
        if (t < BKT_NODES) excl[t] += x;
        __syncthreads();
    }
    if (t < BKT_NODES) {
        int rs = s0 + excl[t] - cnt[t];
        lcur[t] = rs;
        if (t < nnode) {
            rowstart[b * BKT_NODES + t] = rs;
            dis[b * BKT_NODES + t] = rsqrtf((float)(cnt[t] + 1));
        }
    }
    if (b == 0 && t == 0) rowstart[n] = e;
    __syncthreads();
    for (int i = s0 + t; i < s1; i += 256) {
        uint32 v = stage[i];
        int pos = atomicAdd(&lcur[v & (BKT_NODES - 1)], 1);
        csr[pos] = (int)(v >> BKT_SHIFT);
    }
}

// ---------------- weight transpose + bf16 convert (one-time) -------------

__global__ void convw_kernel(const float* __restrict__ W1,
                             const float* __restrict__ W2,
                             unsigned short* __restrict__ w1t,
                             unsigned short* __restrict__ w2t) {
    int i = blockIdx.x * blockDim.x + threadIdx.x;
    if (i < HD * F_IN) {
        int h = i >> 9, k = i & 511;
        w1t[i] = f2bf(W1[k * HD + h]);
    } else {
        int j = i - HD * F_IN;
        if (j < CD * HD) {
            int c = j >> 6, k = j & 63;
            w2t[j] = f2bf(W2[k * CD + c]);
        }
    }
}

// ---------------- MFMA MLP + riemann + init ------------------------------

#define LSTR 72

__global__ __launch_bounds__(256) void mlp_kernel(
    const float* __restrict__ x, const unsigned short* __restrict__ w1t,
    const float* __restrict__ b1, const unsigned short* __restrict__ w2t,
    const float* __restrict__ b2, const float* __restrict__ dis,
    const float* __restrict__ temp, const float* __restrict__ wfn,
    unsigned short* __restrict__ g0, float* __restrict__ hidden, int n) {
    __shared__ __align__(16) unsigned short xb[64 * LSTR];
    __shared__ __align__(16) unsigned short w1b[64 * LSTR];
    __shared__ __align__(16) unsigned short w2b[16 * LSTR];

    const int t = threadIdx.x;
    const int row0 = blockIdx.x * 64;
    const int wave = t >> 6, lane = t & 63;
    const int l15 = lane & 15, lq = lane >> 4;
    const int lrow = (wave << 4) + l15;

    if (t < 128) {
        int cr = t >> 3, part = t & 7;
        *(short8v*)&w2b[cr * LSTR + part * 8] =
            *(const short8v*)&w2t[cr * HD + part * 8];
    }

    float4v acc[4];
#pragma unroll
    for (int i = 0; i < 4; ++i) acc[i] = (float4v)0.0f;

    const int srow = t >> 2, spart = t & 3;
    for (int c = 0; c < F_IN / 64; ++c) {
        __syncthreads();
        {
            int gr = row0 + srow; if (gr >= n) gr = n - 1;
            const float* xp = x + (long)gr * F_IN + c * 64 + spart * 16;
            float4 v0 = *(const float4*)(xp + 0);
            float4 v1 = *(const float4*)(xp + 4);
            float4 v2 = *(const float4*)(xp + 8);
            float4 v3 = *(const float4*)(xp + 12);
            short8v o0, o1;
            o0[0] = (short)f2bf(v0.x); o0[1] = (short)f2bf(v0.y);
            o0[2] = (short)f2bf(v0.z); o0[3] = (short)f2bf(v0.w);
            o0[4] = (short)f2bf(v1.x); o0[5] = (short)f2bf(v1.y);
            o0[6] = (short)f2bf(v1.z); o0[7] = (short)f2bf(v1.w);
            o1[0] = (short)f2bf(v2.x); o1[1] = (short)f2bf(v2.y);
            o1[2] = (short)f2bf(v2.z); o1[3] = (short)f2bf(v2.w);
            o1[4] = (short)f2bf(v3.x); o1[5] = (short)f2bf(v3.y);
            o1[6] = (short)f2bf(v3.z); o1[7] = (short)f2bf(v3.w);
            *(short8v*)&xb[srow * LSTR + spart * 16] = o0;
            *(short8v*)&xb[srow * LSTR + spart * 16 + 8] = o1;
            const unsigned short* wp = w1t + srow * F_IN + c * 64 + spart * 16;
            *(short8v*)&w1b[srow * LSTR + spart * 16] = *(const short8v*)(wp);
            *(short8v*)&w1b[srow * LSTR + spart * 16 + 8] = *(const short8v*)(wp + 8);
        }
        __syncthreads();
#pragma unroll
        for (int st = 0; st < 2; ++st) {
            int kb = st * 32 + lq * 8;
            short8v av = *(const short8v*)&xb[lrow * LSTR + kb];
#pragma unroll
            for (int hf = 0; hf < 4; ++hf) {
                short8v bv = *(const short8v*)&w1b[(hf * 16 + l15) * LSTR + kb];
                acc[hf] = __builtin_amdgcn_mfma_f32_16x16x32_bf16(av, bv, acc[hf], 0, 0, 0);
            }
        }
    }

    __syncthreads();
    {
        int drow = (wave << 4) + (lq << 2);
#pragma unroll
        for (int hf = 0; hf < 4; ++hf) {
            int h = hf * 16 + l15;
            float bv = b1[h];
#pragma unroll
            for (int i = 0; i < 4; ++i) {
                float v = acc[hf][i] + bv;
                v = v > 0.0f ? v : 0.0f;
                xb[(drow + i) * LSTR + h] = f2bf(v);
            }
        }
    }
    __syncthreads();

    float4v acc2 = (float4v)0.0f;
#pragma unroll
    for (int st = 0; st < 2; ++st) {
        int kb = st * 32 + lq * 8;
        short8v av = *(const short8v*)&xb[lrow * LSTR + kb];
        short8v bv = *(const short8v*)&w2b[l15 * LSTR + kb];
        acc2 = __builtin_amdgcn_mfma_f32_16x16x32_bf16(av, bv, acc2, 0, 0, 0);
    }

    {
        const int cc = l15;
        const int drow = (wave << 4) + (lq << 2);
        float b2c = b2[cc];
        float wabs = fabsf(wfn[cc]);
        float o[4], p[4];
#pragma unroll
        for (int i = 0; i < 4; ++i) {
            o[i] = acc2[i] + b2c;
            p[i] = o[i] * o[i] * wabs;
        }
#pragma unroll
        for (int off = 1; off < 16; off <<= 1) {
#pragma unroll
            for (int i = 0; i < 4; ++i) p[i] += __shfl_xor(p[i], off);
        }
        float t0 = temp[0];
#pragma unroll
        for (int i = 0; i < 4; ++i) {
            int grow = row0 + drow + i;
            if (grow < n) {
                float inv = 1.0f / (sqrtf(p[i] + 0.01f) + 0.01f);
                float hn = o[i] * inv;
                float d = dis[grow];
                hidden[(long)grow * CD + cc] = t0 * hn;
                g0[(long)grow * CD + cc] = f2bf(d * hn);
            }
        }
    }
}

// ---------------- fused hop: grid-stride, node-pipelined (r7, best) ------
// 8192 waves (32/CU), ~12 nodes each; node = sweep*NW + wave keeps active
// waves on consecutive nodes. Depth-1 software pipeline: next node's
// rowstart/dis/self/hidden AND first-32-edge csr indices in flight while
// the current node gathers/reduces. 16 edge-slots x 4 feat-lanes.

__global__ __launch_bounds__(256) void hop_kernel(
    const unsigned short* __restrict__ g, unsigned short* __restrict__ gn,
    float* __restrict__ hidden, const float* __restrict__ dis,
    const int* __restrict__ rowstart, const int* __restrict__ csr,
    const float* __restrict__ temp, const float* __restrict__ wfn,
    int kidx, int writeg, int n, int etot) {
    const int wv = (blockIdx.x << 2) + (threadIdx.x >> 6);
    const int NW = gridDim.x << 2;
    if (wv >= n) return;
    const int lane = threadIdx.x & 63;
    const int slot = lane >> 2, fl = lane & 3;
    const float4 wq = *(const float4*)(wfn + (fl << 2));
    const float wx = fabsf(wq.x), wy = fabsf(wq.y),
                wz = fabsf(wq.z), ww = fabsf(wq.w);
    const float tk = temp[kidx];

    // prologue: state for first node
    int node = wv;
    int rs0 = rowstart[node], rs1 = rowstart[node + 1];
    float d = dis[node];
    ushort4 sv = *(const ushort4*)(g + ((long)node << 4) + (fl << 2));
    float4 hv;
    if (slot == 0) hv = *(const float4*)(hidden + ((long)node << 4) + (fl << 2));
    int c0 = csr[min(rs0 + slot, etot - 1)];
    int c1 = csr[min(rs0 + slot + 16, etot - 1)];

    for (;;) {
        const int nnext = node + NW;
        const bool has_next = nnext < n;

        // (1) issue next node's independent loads
        int rs0n, rs1n; float dn; ushort4 svn; float4 hvn;
        if (has_next) {
            rs0n = rowstart[nnext];
            rs1n = rowstart[nnext + 1];
            dn = dis[nnext];
            svn = *(const ushort4*)(g + ((long)nnext << 4) + (fl << 2));
            if (slot == 0)
                hvn = *(const float4*)(hidden + ((long)nnext << 4) + (fl << 2));
        }

        // (2) gather current node (first 32 edges via prefetched c0/c1)
        float a0 = 0.f, a1 = 0.f, a2 = 0.f, a3 = 0.f;
        if (rs0 + slot < rs1) {
            ushort4 v1 = *(const ushort4*)(g + ((long)c0 << 4) + (fl << 2));
            a0 += bf2f(v1.x); a1 += bf2f(v1.y); a2 += bf2f(v1.z); a3 += bf2f(v1.w);
        }
        if (rs0 + slot + 16 < rs1) {
            ushort4 v2 = *(const ushort4*)(g + ((long)c1 << 4) + (fl << 2));
            a0 += bf2f(v2.x); a1 += bf2f(v2.y); a2 += bf2f(v2.z); a3 += bf2f(v2.w);
        }
        for (int e2 = rs0 + slot + 32; e2 < rs1; e2 += 16) {
            int s1 = csr[e2];
            ushort4 v = *(const ushort4*)(g + ((long)s1 << 4) + (fl << 2));
            a0 += bf2f(v.x); a1 += bf2f(v.y); a2 += bf2f(v.z); a3 += bf2f(v.w);
        }

        // (3) reduce + riemann + writes
#pragma unroll
        for (int off = 4; off < 64; off <<= 1) {
            a0 += __shfl_xor(a0, off);
            a1 += __shfl_xor(a1, off);
            a2 += __shfl_xor(a2, off);
            a3 += __shfl_xor(a3, off);
        }
        a0 = (a0 + bf2f(sv.x)) * d;
        a1 = (a1 + bf2f(sv.y)) * d;
        a2 = (a2 + bf2f(sv.z)) * d;
        a3 = (a3 + bf2f(sv.w)) * d;
        float p = a0 * a0 * wx + a1 * a1 * wy + a2 * a2 * wz + a3 * a3 * ww;
        p += __shfl_xor(p, 1);
        p += __shfl_xor(p, 2);
        float inv = 1.0f / (sqrtf(p + 0.01f) + 0.01f);
        float h0 = a0 * inv, h1 = a1 * inv, h2 = a2 * inv, h3 = a3 * inv;
        if (slot == 0) {
            long base = ((long)node << 4) + (fl << 2);
            hv.x = fmaf(tk, h0, hv.x);
            hv.y = fmaf(tk, h1, hv.y);
            hv.z = fmaf(tk, h2, hv.z);
            hv.w = fmaf(tk, h3, hv.w);
            *(float4*)(hidden + base) = hv;
            if (writeg) {
                ushort4 o;
                o.x = f2bf(d * h0); o.y = f2bf(d * h1);
                o.z = f2bf(d * h2); o.w = f2bf(d * h3);
                *(ushort4*)(gn + base) = o;
            }
        }

        if (!has_next) break;

        // (4) prefetch next node's first-32-edge csr indices
        int c0n = csr[min(rs0n + slot, etot - 1)];
        int c1n = csr[min(rs0n + slot + 16, etot - 1)];

        // (5) rotate
        node = nnext;
        rs0 = rs0n; rs1 = rs1n; d = dn; sv = svn; hv = hvn;
        c0 = c0n; c1 = c1n;
    }
}

// ---------------- launch ----------------

static inline long align4up(long w) { return (w + 3) & ~3L; }

extern "C" void kernel_launch(void* const* d_in, const int* in_sizes, int n_in,
                              void* d_out, int out_size, void* d_ws, size_t ws_size,
                              hipStream_t stream) {
    const float* x          = (const float*)d_in[0];
    const int*   edge_index = (const int*)d_in[1];
    const float* W1         = (const float*)d_in[2];
    const float* b1         = (const float*)d_in[3];
    const float* W2         = (const float*)d_in[4];
    const float* b2         = (const float*)d_in[5];
    const float* temp       = (const float*)d_in[6];
    const float* w_for_norm = (const float*)d_in[7];
    float* hidden = (float*)d_out;

    const int n = in_sizes[0] / F_IN;
    const int e = in_sizes[1] / 2;
    const int* rows = edge_index;        // sources
    const int* cols = edge_index + e;    // destinations
    const int nb = (n + BKT_NODES - 1) / BKT_NODES;

    long off = 0;
    int* wsI = (int*)d_ws;
    int* bcnt      = wsI + off; off = align4up(off + NBKT_MAX);
    int* bstart    = wsI + off; off = align4up(off + NBKT_MAX + 1);
    int* bcur      = wsI + off; off = align4up(off + NBKT_MAX);
    int* rowstart  = wsI + off; off = align4up(off + n + 1);
    float* dis     = (float*)(wsI + off); off = align4up(off + n);
    uint32* stage  = (uint32*)(wsI + off); off = align4up(off + e);
    int* csr       = wsI + off; off = align4up(off + e);
    unsigned short* w1t = (unsigned short*)(wsI + off); off = align4up(off + HD * F_IN / 2);
    unsigned short* w2t = (unsigned short*)(wsI + off); off = align4up(off + CD * HD / 2);
    unsigned short* gA  = (unsigned short*)(wsI + off); off = align4up(off + n * 8);
    unsigned short* gB  = (unsigned short*)(wsI + off); off = align4up(off + n * 8);

    const int B = 256;
    const int nbC = (e + EPB - 1) / EPB;

    zero_kernel<<<(nb + B - 1) / B, B, 0, stream>>>(bcnt, nb);
    bucket_hist_kernel<<<nbC, B, 0, stream>>>(cols, bcnt, e, nb);
    bucket_scan_kernel<<<1, B, 0, stream>>>(bcnt, bstart, bcur, nb);
    scatter_bin_kernel<<<nbC, B, 0, stream>>>(rows, cols, bcur, stage, e, nb);
    bucket_sort_kernel<<<nb, B, 0, stream>>>(stage, bstart, rowstart, dis, csr, n, e);
    convw_kernel<<<(HD * F_IN + CD * HD + B - 1) / B, B, 0, stream>>>(W1, W2, w1t, w2t);

    mlp_kernel<<<(n + 63) / 64, B, 0, stream>>>(x, w1t, b1, w2t, b2, dis, temp,
                                                w_for_norm, gA, hidden, n);

    unsigned short* gsrc = gA;
    unsigned short* gdst = gB;
    for (int k = 1; k <= K_HOPS; ++k) {
        hop_kernel<<<HOP_BLOCKS, B, 0, stream>>>(
            gsrc, gdst, hidden, dis, rowstart, csr, temp, w_for_norm,
            k, (k < K_HOPS) ? 1 : 0, n, e);
        unsigned short* tmp = gsrc; gsrc = gdst; gdst = tmp;
    }
}